// Round 2
// 3073.235 us; speedup vs baseline: 3.0931x; 3.0931x over previous
//
#include <hip/hip_runtime.h>
#include <hip/hip_fp16.h>
#include <cstdint>

// Problem constants
#define BNW   4096           // windows
#define L     49             // tokens per window
#define C     512            // channels
#define NH    16             // heads
#define HD    32             // head dim
#define M_TOT (BNW * L)      // 200704 rows
#define N_QKV (3 * C)        // 1536
#define KDIM  512
#define CH_STRIDE ((size_t)M_TOT)  // qkvT row stride (per channel)

typedef unsigned short u16;
typedef unsigned int   u32;
typedef __attribute__((ext_vector_type(8))) _Float16 f16x8;  // 4 VGPRs, MFMA A/B frag
typedef __attribute__((ext_vector_type(4))) float    f32x4;  // MFMA C/D frag

// fp32 -> (hi, lo) fp16 split, RNE. hi + lo represents x to ~2^-24 rel.
__device__ __forceinline__ void split_f16(float v, u16& h, u16& l) {
  const __half hh = __float2half(v);
  h = __half_as_ushort(hh);
  l = __half_as_ushort(__float2half(v - __half2float(hh)));
}

// async global->LDS, 16B per lane. LDS dest = wave-uniform base + lane*16.
__device__ __forceinline__ void glds16(const void* g, void* s) {
  const __attribute__((address_space(1))) u32* gp =
      (const __attribute__((address_space(1))) u32*)g;
  __attribute__((address_space(3))) u32* lp =
      (__attribute__((address_space(3))) u32*)s;
  __builtin_amdgcn_global_load_lds(gp, lp, 16, 0, 0);
}

// ---------------------------------------------------------------------------
// Kernel 0a: split x (fp32 [m][k]) -> xh, xl (fp16-in-u16, same layout)
// ---------------------------------------------------------------------------
__global__ __launch_bounds__(256) void split_x_f16(
    const float* __restrict__ x, u16* __restrict__ xh, u16* __restrict__ xl) {
  const size_t i = (size_t)blockIdx.x * 256 + threadIdx.x;  // float4 index
  const float4 v = ((const float4*)x)[i];
  u16 h0, h1, h2, h3, l0, l1, l2, l3;
  split_f16(v.x, h0, l0); split_f16(v.y, h1, l1);
  split_f16(v.z, h2, l2); split_f16(v.w, h3, l3);
  uint2 hp, lp2;
  hp.x  = (u32)h0 | ((u32)h1 << 16); hp.y  = (u32)h2 | ((u32)h3 << 16);
  lp2.x = (u32)l0 | ((u32)l1 << 16); lp2.y = (u32)l2 | ((u32)l3 << 16);
  ((uint2*)xh)[i] = hp;
  ((uint2*)xl)[i] = lp2;
}

// ---------------------------------------------------------------------------
// Kernel 0b: split + transpose weights: w [K][N] fp32 -> wT hi/lo [N][K] fp16
// ---------------------------------------------------------------------------
__global__ __launch_bounds__(256) void split_wT_f16(
    const float* __restrict__ w, u16* __restrict__ wth, u16* __restrict__ wtl,
    const int N) {
  __shared__ float tile[32][33];
  const int k0 = blockIdx.x * 32;
  const int n0 = blockIdx.y * 32;
  const int t = threadIdx.x, tx = t & 31, ty = t >> 5;
#pragma unroll
  for (int r = ty; r < 32; r += 8)
    tile[r][tx] = w[(size_t)(k0 + r) * N + n0 + tx];
  __syncthreads();
#pragma unroll
  for (int r = ty; r < 32; r += 8) {
    u16 h, l;
    split_f16(tile[tx][r], h, l);   // = w[k0+tx][n0+r]
    const size_t o = (size_t)(n0 + r) * KDIM + k0 + tx;
    wth[o] = h; wtl[o] = l;
  }
}

// ---------------------------------------------------------------------------
// Kernel 1/3: fp16x3-split MFMA GEMM. out = A(fp32 via hi+lo) * B + bias.
// A: [M][K] as hi/lo fp16. B: [N][K] (pre-transposed) hi/lo fp16.
// 128x128 tile, BK=32, 4 waves (2x2), 4x4 frags of 16x16x32 MFMA per wave.
// 3 MFMA per frag-pair: ah*bh + al*bh + ah*bl (lo*lo dropped, ~2^-24).
// TRANS_OUT=1: out[n][m] (+bias[n])   TRANS_OUT=0: out[m][n] (+bias[n])
// ---------------------------------------------------------------------------
template <int TRANS_OUT>
__global__ __launch_bounds__(256) void gemm_f16x3(
    const u16* __restrict__ Agh, const u16* __restrict__ Agl,
    const u16* __restrict__ Bgh, const u16* __restrict__ Bgl,
    const float* __restrict__ bias, float* __restrict__ out,
    const int nbn, const size_t ostride) {
  __shared__ __align__(16) u16 sAh[128 * 32];
  __shared__ __align__(16) u16 sAl[128 * 32];
  __shared__ __align__(16) u16 sBh[128 * 32];
  __shared__ __align__(16) u16 sBl[128 * 32];

  // bijective XCD swizzle (gridDim.x % 8 == 0): each XCD walks contiguous
  // logical tiles; n is the fast dim so the 128-row A-panel stays L2-hot.
  const int cpx  = (int)gridDim.x >> 3;
  const int lid  = ((int)blockIdx.x & 7) * cpx + ((int)blockIdx.x >> 3);
  const int mblk = lid / nbn;
  const int nblk = lid - mblk * nbn;
  const size_t m0 = (size_t)mblk * 128;
  const int    n0 = nblk * 128;

  const int t = threadIdx.x;
  const int w = t >> 6, l = t & 63;
  const int wr = w >> 1, wc = w & 1;          // wave's 64x64 quadrant
  const int crow = l >> 2, ck = (l & 3) * 8;  // staging: lane -> (row, k8)
  const int lr = l & 15, lk8 = (l >> 4) * 8;  // frag: row/col + k-chunk

  // staging source bases (this wave owns chunks 2w, 2w+1 of each tile)
  const size_t aB0 = (m0 + (size_t)((w * 2 + 0) * 16 + crow)) * KDIM + ck;
  const size_t aB1 = (m0 + (size_t)((w * 2 + 1) * 16 + crow)) * KDIM + ck;
  const size_t bB0 = ((size_t)(n0 + (w * 2 + 0) * 16 + crow)) * KDIM + ck;
  const size_t bB1 = ((size_t)(n0 + (w * 2 + 1) * 16 + crow)) * KDIM + ck;
  const int c0 = (w * 2 + 0) * 512, c1 = (w * 2 + 1) * 512;  // LDS u16 offs

  f32x4 acc[4][4];
#pragma unroll
  for (int i = 0; i < 4; ++i)
#pragma unroll
    for (int j = 0; j < 4; ++j)
#pragma unroll
      for (int r = 0; r < 4; ++r) acc[i][j][r] = 0.f;

  for (int k0 = 0; k0 < KDIM; k0 += 32) {
    glds16(Agh + aB0 + k0, sAh + c0);
    glds16(Agh + aB1 + k0, sAh + c1);
    glds16(Agl + aB0 + k0, sAl + c0);
    glds16(Agl + aB1 + k0, sAl + c1);
    glds16(Bgh + bB0 + k0, sBh + c0);
    glds16(Bgh + bB1 + k0, sBh + c1);
    glds16(Bgl + bB0 + k0, sBl + c0);
    glds16(Bgl + bB1 + k0, sBl + c1);
    __syncthreads();  // compiler drains vmcnt before s_barrier

    f16x8 ah[4], al[4], bh[4], bl[4];
#pragma unroll
    for (int f = 0; f < 4; ++f) {
      const int ra = (wr * 64 + f * 16 + lr) * 32 + lk8;
      const int rb = (wc * 64 + f * 16 + lr) * 32 + lk8;
      ah[f] = *(const f16x8*)(sAh + ra);
      al[f] = *(const f16x8*)(sAl + ra);
      bh[f] = *(const f16x8*)(sBh + rb);
      bl[f] = *(const f16x8*)(sBl + rb);
    }
#pragma unroll
    for (int i = 0; i < 4; ++i)
#pragma unroll
      for (int j = 0; j < 4; ++j) {
        acc[i][j] = __builtin_amdgcn_mfma_f32_16x16x32_f16(ah[i], bh[j], acc[i][j], 0, 0, 0);
        acc[i][j] = __builtin_amdgcn_mfma_f32_16x16x32_f16(al[i], bh[j], acc[i][j], 0, 0, 0);
        acc[i][j] = __builtin_amdgcn_mfma_f32_16x16x32_f16(ah[i], bl[j], acc[i][j], 0, 0, 0);
      }
    __syncthreads();
  }

  // epilogue. C/D frag: col = l&15 (n), row = (l>>4)*4 + reg (m)
  const int lk4 = (l >> 4) * 4;
#pragma unroll
  for (int j = 0; j < 4; ++j) {
    const int n = n0 + wc * 64 + j * 16 + lr;
    const float bn = bias[n];
#pragma unroll
    for (int i = 0; i < 4; ++i) {
      const size_t m = m0 + wr * 64 + i * 16 + lk4;
      if (TRANS_OUT) {
        float4 o;
        o.x = acc[i][j][0] + bn; o.y = acc[i][j][1] + bn;
        o.z = acc[i][j][2] + bn; o.w = acc[i][j][3] + bn;
        *(float4*)(out + (size_t)n * ostride + m) = o;  // m contiguous over reg
      } else {
#pragma unroll
        for (int r = 0; r < 4; ++r)
          out[(m + r) * ostride + n] = acc[i][j][r] + bn;
      }
    }
  }
}

// ---------------------------------------------------------------------------
// Kernel 2: per-(window, head) attention (unchanged math, fp32). Epilogue
// writes y directly as fp16 hi/lo splits for the proj GEMM (no fp32 y array).
// ---------------------------------------------------------------------------
__global__ __launch_bounds__(64) void attn_win(
    const float* __restrict__ qkvT, const float* __restrict__ mask,
    const float* __restrict__ bias_table, const int* __restrict__ index_table,
    u16* __restrict__ yh, u16* __restrict__ yl) {
  __shared__ float k_s[L * HD];  // 1568
  __shared__ float v_s[L * HD];  // 1568
  const int bh = blockIdx.x;
  const int b = bh >> 4;
  const int h = bh & 15;
  // contiguous q/k/v chunks thanks to the transposed qkv layout (faithful to
  // the reference's channel-major reshape quirk)
  const size_t base = (size_t)(b >> 3) * CH_STRIDE +
                      (size_t)((b & 7) * 512 + h * 32) * 49;
  const float* uq = qkvT + base;
  const float* uk = uq + (size_t)512 * CH_STRIDE;
  const float* uv = uq + (size_t)1024 * CH_STRIDE;
  const int t = threadIdx.x;

  for (int i = t; i < (L * HD) / 4; i += 64) {  // 392 float4 each
    ((float4*)k_s)[i] = ((const float4*)uk)[i];
    ((float4*)v_s)[i] = ((const float4*)uv)[i];
  }

  float qr[HD];
  if (t < L) {
#pragma unroll
    for (int i = 0; i < 8; ++i) {
      const float4 qv = ((const float4*)(uq + t * HD))[i];
      qr[i * 4 + 0] = qv.x; qr[i * 4 + 1] = qv.y;
      qr[i * 4 + 2] = qv.z; qr[i * 4 + 3] = qv.w;
    }
  }
  __syncthreads();

  if (t < L) {
    const float* mrow = mask + (size_t)(b & 63) * (L * L) + t * L;
    const int*   irow = index_table + t * L;
    float s[L];
#pragma unroll
    for (int m = 0; m < L; ++m) {
      float acc = 0.f;
#pragma unroll
      for (int d = 0; d < HD; ++d) acc += qr[d] * k_s[m * HD + d];
      s[m] = acc + bias_table[irow[m] * NH + h] + mrow[m];
    }
    float mx = s[0];
#pragma unroll
    for (int m = 1; m < L; ++m) mx = fmaxf(mx, s[m]);
    float sum = 0.f;
#pragma unroll
    for (int m = 0; m < L; ++m) { s[m] = __expf(s[m] - mx); sum += s[m]; }
    const float inv = 1.f / sum;
    float o[HD];
#pragma unroll
    for (int d = 0; d < HD; ++d) o[d] = 0.f;
#pragma unroll
    for (int m = 0; m < L; ++m) {
      const float p = s[m] * inv;
#pragma unroll
      for (int d = 0; d < HD; ++d) o[d] += p * v_s[m * HD + d];
    }
    const size_t yo = (size_t)b * (L * C) + (size_t)t * C + h * HD;
    u32 hp[16], lp[16];
#pragma unroll
    for (int d2 = 0; d2 < 16; ++d2) {
      u16 h0, h1, l0, l1;
      split_f16(o[2 * d2 + 0], h0, l0);
      split_f16(o[2 * d2 + 1], h1, l1);
      hp[d2] = (u32)h0 | ((u32)h1 << 16);
      lp[d2] = (u32)l0 | ((u32)l1 << 16);
    }
#pragma unroll
    for (int q = 0; q < 4; ++q) {
      uint4 hv, lv;
      hv.x = hp[4 * q]; hv.y = hp[4 * q + 1]; hv.z = hp[4 * q + 2]; hv.w = hp[4 * q + 3];
      lv.x = lp[4 * q]; lv.y = lp[4 * q + 1]; lv.z = lp[4 * q + 2]; lv.w = lp[4 * q + 3];
      *(uint4*)(yh + yo + q * 8) = hv;
      *(uint4*)(yl + yo + q * 8) = lv;
    }
  }
}

// ---------------------------------------------------------------------------
extern "C" void kernel_launch(void* const* d_in, const int* in_sizes, int n_in,
                              void* d_out, int out_size, void* d_ws, size_t ws_size,
                              hipStream_t stream) {
  const float* x          = (const float*)d_in[0];
  const float* mask       = (const float*)d_in[1];
  const float* w_qkv      = (const float*)d_in[2];
  const float* b_qkv      = (const float*)d_in[3];
  const float* w_proj     = (const float*)d_in[4];
  const float* b_proj     = (const float*)d_in[5];
  const float* bias_table = (const float*)d_in[6];
  const int*   index_tab  = (const int*)d_in[7];
  float* out = (float*)d_out;

  // d_ws layout — byte-identical footprint to the proven round-0 kernel
  // (qkvT 1.233 GB + 411 MB):
  //   qkvT   : 1536 x 200704 fp32
  //   xh, xl : 200704 x 512 fp16 each (= old y's 411 MB); reused as yh/yl
  //            after the qkv GEMM (x splits dead by then)
  // Weight splits live in DEAD buffers, not past the footprint:
  //   wth/wtl (qkv, 3 MB)  -> head of d_out (out written only by final GEMM)
  //   wph/wpl (proj, 1 MB) -> head of qkvT region, split AFTER attn consumed it
  float* qkvT = (float*)d_ws;
  u16* xh  = (u16*)(qkvT + (size_t)N_QKV * M_TOT);
  u16* xl  = xh + (size_t)M_TOT * KDIM;
  u16* yh  = xh;  // alias: x splits dead after qkv GEMM
  u16* yl  = xl;
  u16* wth = (u16*)d_out;                    // dead before proj GEMM writes out
  u16* wtl = wth + (size_t)N_QKV * KDIM;
  u16* wph = (u16*)qkvT;                     // qkvT dead after attn_win
  u16* wpl = wph + (size_t)C * KDIM;

  split_x_f16<<<(M_TOT * KDIM / 4) / 256, 256, 0, stream>>>(x, xh, xl);
  split_wT_f16<<<dim3(KDIM / 32, N_QKV / 32), 256, 0, stream>>>(w_qkv, wth, wtl, N_QKV);

  gemm_f16x3<1><<<(M_TOT / 128) * (N_QKV / 128), 256, 0, stream>>>(
      xh, xl, wth, wtl, b_qkv, qkvT, N_QKV / 128, (size_t)M_TOT);

  attn_win<<<BNW * NH, 64, 0, stream>>>(qkvT, mask, bias_table, index_tab, yh, yl);

  split_wT_f16<<<dim3(KDIM / 32, C / 32), 256, 0, stream>>>(w_proj, wph, wpl, C);

  gemm_f16x3<0><<<(M_TOT / 128) * (C / 128), 256, 0, stream>>>(
      yh, yl, wph, wpl, b_proj, out, C / 128, (size_t)C);
}